// Round 13
// baseline (214.156 us; speedup 1.0000x reference)
//
#include <hip/hip_runtime.h>
#include <math.h>

#define N_NODES 100000
#define R_REL   1000
#define T_TRI   600000
#define D_DIM   128
#define OUT_STRIDE 640

typedef unsigned int  u32;
typedef unsigned short u16;

template<int CTRL>
__device__ __forceinline__ float dpp_add(float x) {
    int xi = __float_as_int(x);
    int r = __builtin_amdgcn_update_dpp(xi, xi, CTRL, 0xf, 0xf, false);
    return x + __int_as_float(r);
}
__device__ __forceinline__ float row16_sum(float v) {
    v = dpp_add<0x121>(v);
    v = dpp_add<0x122>(v);
    v = dpp_add<0x124>(v);
    v = dpp_add<0x128>(v);
    return v;
}
__device__ __forceinline__ float wave_sum(float v) {
    #pragma unroll
    for (int off = 32; off > 0; off >>= 1) v += __shfl_xor(v, off);
    return v;
}
__device__ __forceinline__ float half32_sum(float v) {
    v = row16_sum(v);
    v += __shfl_xor(v, 16);
    return v;
}
__device__ __forceinline__ float fast_tanh(float x) {
    float e = __expf(2.f * x);
    return 1.f - __fdividef(2.f, e + 1.f);
}
__device__ __forceinline__ float4 tanh4(float4 v) {
    float4 o; o.x = fast_tanh(v.x); o.y = fast_tanh(v.y);
    o.z = fast_tanh(v.z); o.w = fast_tanh(v.w);
    return o;
}
__device__ __forceinline__ float dot4(float4 a, float4 b) {
    return a.x*b.x + a.y*b.y + a.z*b.z + a.w*b.w;
}
__device__ __forceinline__ u32 bfr(float x) {
    u32 u = __float_as_uint(x);
    return (u + 0x7fffu + ((u >> 16) & 1u)) >> 16;
}
__device__ __forceinline__ uint2 pack_bf4(float4 v) {
    uint2 p;
    p.x = bfr(v.x) | (bfr(v.y) << 16);
    p.y = bfr(v.z) | (bfr(v.w) << 16);
    return p;
}
__device__ __forceinline__ void unpack_bf8(uint4 v, float f[8]) {
    f[0] = __uint_as_float(v.x << 16); f[1] = __uint_as_float(v.x & 0xffff0000u);
    f[2] = __uint_as_float(v.y << 16); f[3] = __uint_as_float(v.y & 0xffff0000u);
    f[4] = __uint_as_float(v.z << 16); f[5] = __uint_as_float(v.z & 0xffff0000u);
    f[6] = __uint_as_float(v.w << 16); f[7] = __uint_as_float(v.w & 0xffff0000u);
}

// prep: tanh+pack chunk0, normalized-rel, rowptrs, packed edge array
__global__ void k_prep(const float* __restrict__ feat, const float* __restrict__ rel,
                       const float* __restrict__ attk, const float* __restrict__ r_val,
                       float* __restrict__ out, u16* __restrict__ bf0,
                       u16* __restrict__ relu_bf, float* __restrict__ wtab,
                       const int* __restrict__ adj, const int* __restrict__ r_index,
                       const int* __restrict__ hn_rows,
                       int* __restrict__ rpa, int* __restrict__ rph,
                       int2* __restrict__ epack) {
    int tid = threadIdx.x;
    int gt = blockIdx.x * blockDim.x + tid;
    int gstride = gridDim.x * blockDim.x;

    for (int i = gt; i < N_NODES * D_DIM / 4; i += gstride) {
        int n = i >> 5, d4 = i & 31;
        float4 v = ((const float4*)feat)[i];
        float4 t = tanh4(v);
        ((float4*)(out + (size_t)n * OUT_STRIDE))[d4] = t;
        ((uint2*)(bf0 + (size_t)n * D_DIM))[d4] = pack_bf4(t);
    }
    int gw = gt >> 6, lane = tid & 63;
    int nwaves = gstride >> 6;
    for (int r = gw; r < R_REL; r += nwaves) {
        float2 a  = ((const float2*)rel)[r * 64 + lane];
        float2 k0 = ((const float2*)attk)[lane];
        float2 k1 = ((const float2*)(attk + D_DIM))[lane];
        float nrm2 = wave_sum(a.x * a.x + a.y * a.y);
        float d0 = wave_sum(a.x * k0.x + a.y * k0.y);
        float d1 = wave_sum(a.x * k1.x + a.y * k1.y);
        float inv = __frsqrt_rn(nrm2);
        ((u32*)relu_bf)[r * 64 + lane] = bfr(a.x * inv) | (bfr(a.y * inv) << 16);
        if (lane == 0) {
            wtab[r]         = __expf(d0 * inv);
            wtab[R_REL + r] = __expf(d1 * inv);
        }
    }
    for (int i = gt; i < 2 * (N_NODES + 1); i += gstride) {
        const int* rows; int* p; int n;
        if (i <= N_NODES) { rows = adj; p = rpa; n = i; }
        else { rows = hn_rows; p = rph; n = i - (N_NODES + 1); }
        int lo = 0, hi = T_TRI;
        while (lo < hi) { int m = (lo + hi) >> 1; if (rows[m] < n) lo = m + 1; else hi = m; }
        p[n] = lo;
    }
    // packed edges: (col, rel | zflag<<31)
    for (int t = gt; t < T_TRI; t += gstride) {
        int c  = adj[T_TRI + t];
        int rt = r_index[T_TRI + t];
        if (r_val[t] == 0.f) rt |= 0x80000000;
        epack[t] = make_int2(c, rt);
    }
}

// 2 rows/wave, 2x16-lane subgroups per row, 8 dims/lane.  Simplified single
// loop (no SW pipeline), packed edges, 64-VGPR target for 8 waves/SIMD.
__global__ __launch_bounds__(256, 8) void k_nr_layer(
    float* __restrict__ outbuf, int out_off,
    const u16* __restrict__ in_bf,
    u16* __restrict__ out_bf,
    const int* __restrict__ row_ptr,
    const int2* __restrict__ epack,
    const u16* __restrict__ relu_bf,
    const float* __restrict__ wtab,
    const float* __restrict__ ha,
    float* __restrict__ eproj_out) {
    __shared__ float s_w[4][64];
    int wslot = threadIdx.x >> 6;
    int lane  = threadIdx.x & 63;
    int wid2  = (blockIdx.x * blockDim.x + threadIdx.x) >> 6;
    int row   = wid2 * 2 + (lane >> 5);
    if (row >= N_NODES) return;
    int ll  = lane & 31;
    int sgl = (lane >> 4) & 1;
    int sl  = lane & 15;
    int beg = row_ptr[row], end = row_ptr[row + 1];
    int deg = end - beg;
    float* orow = outbuf + (size_t)row * OUT_STRIDE + out_off;

    if (deg == 0) {
        float4 z = {0.f,0.f,0.f,0.f};
        ((float4*)orow)[ll] = z;
        if (out_bf != nullptr && ll < 16) {
            uint4 zz = {0u,0u,0u,0u};
            ((uint4*)(out_bf + (size_t)row * D_DIM))[ll] = zz;
        }
        if (ha != nullptr && ll == 0) eproj_out[row] = 1.f;
        return;
    }

    // pass A: lane ll owns edge beg+ll
    int  t0 = beg + ll;
    bool va = t0 < end;
    int2 ea = epack[va ? t0 : beg];
    int  rt_a = ea.y & 0x7fffffff;
    bool z_a  = ea.y < 0;
    float w_a = va ? (z_a ? 1.f : wtab[rt_a]) : 0.f;
    float lsum = w_a;
    for (int t = t0 + 32; t < end; t += 32) {          // deg>32 guard
        int2 e = epack[t];
        lsum += (e.y < 0) ? 1.f : wtab[e.y & 0x7fffffff];
    }
    float inv_s = 1.f / half32_sum(lsum);
    float sw = w_a * inv_s;
    s_w[wslot][lane] = z_a ? -sw : sw;
    int hb = lane & 32;

    float acc[8] = {0.f,0.f,0.f,0.f,0.f,0.f,0.f,0.f};
    int niter = (deg + 1) >> 1;
    for (int it = 0; it < niter; ++it) {
        int idx = 2 * it + sgl;
        int t = beg + idx;
        bool valid = t < end;
        int2 e = epack[valid ? t : beg];
        int c  = e.x;
        int rt = e.y & 0x7fffffff;
        float sv;
        if (idx < 32) sv = s_w[wslot][hb + idx];       // signed; 0 beyond deg
        else {
            bool z = e.y < 0;
            float wv = valid ? (z ? 1.f : wtab[rt]) * inv_s : 0.f;
            sv = z ? -wv : wv;
        }
        float w = fabsf(sv);
        uint4 F = ((const uint4*)(in_bf   + (size_t)c  * D_DIM))[sl];
        uint4 U = ((const uint4*)(relu_bf + (size_t)rt * D_DIM))[sl];
        float nf[8], uf[8];
        unpack_bf8(F, nf); unpack_bf8(U, uf);
        float pd = 0.f;
        #pragma unroll
        for (int j = 0; j < 8; ++j) pd += nf[j] * uf[j];
        pd = row16_sum(pd);
        float bt = (sv < 0.f) ? 0.f : 2.f * w * pd;
        #pragma unroll
        for (int j = 0; j < 8; ++j) acc[j] += w * nf[j] - bt * uf[j];
    }

    #pragma unroll
    for (int j = 0; j < 8; ++j) acc[j] += __shfl_xor(acc[j], 16);

    float4 q = (sgl == 0) ? make_float4(acc[0], acc[1], acc[2], acc[3])
                          : make_float4(acc[4], acc[5], acc[6], acc[7]);
    float4 tq = tanh4(q);
    ((float4*)orow)[2 * sl + sgl] = tq;
    if (out_bf != nullptr)
        ((uint2*)(out_bf + (size_t)row * D_DIM))[2 * sl + sgl] = pack_bf4(tq);
    if (ha != nullptr) {
        const float4* ha4 = (const float4*)ha;
        float pdp = dot4(tq, ha4[2 * sl + sgl]);
        pdp = row16_sum(pdp);
        pdp += __shfl_xor(pdp, 16);
        if (ll == 0) eproj_out[row] = __expf(pdp);
    }
}

__global__ __launch_bounds__(256, 8) void k_high_layer(
    float* __restrict__ outbuf, int out_off,
    const u16* __restrict__ in_bf,
    u16* __restrict__ out_bf,
    const int* __restrict__ row_ptr,
    const int* __restrict__ hcol,
    const float* __restrict__ eproj,
    const float* __restrict__ ha,
    float* __restrict__ eproj_out) {
    __shared__ float s_w[4][64];
    int wslot = threadIdx.x >> 6;
    int lane  = threadIdx.x & 63;
    int wid2  = (blockIdx.x * blockDim.x + threadIdx.x) >> 6;
    int row   = wid2 * 2 + (lane >> 5);
    if (row >= N_NODES) return;
    int ll  = lane & 31;
    int sgl = (lane >> 4) & 1;
    int sl  = lane & 15;
    int beg = row_ptr[row], end = row_ptr[row + 1];
    int deg = end - beg;
    float* orow = outbuf + (size_t)row * OUT_STRIDE + out_off;

    if (deg == 0) {
        float4 z = {0.f,0.f,0.f,0.f};
        ((float4*)orow)[ll] = z;
        if (out_bf != nullptr && ll < 16) {
            uint4 zz = {0u,0u,0u,0u};
            ((uint4*)(out_bf + (size_t)row * D_DIM))[ll] = zz;
        }
        if (ha != nullptr && ll == 0) eproj_out[row] = 1.f;
        return;
    }

    int  t0 = beg + ll;
    bool va = t0 < end;
    float e_a = va ? eproj[hcol[va ? t0 : beg]] : 0.f;
    float lsum = e_a;
    for (int t = t0 + 32; t < end; t += 32)
        lsum += eproj[hcol[t]];
    float inv_s = 1.f / half32_sum(lsum);
    s_w[wslot][lane] = e_a * inv_s;
    int hb = lane & 32;

    float acc[8] = {0.f,0.f,0.f,0.f,0.f,0.f,0.f,0.f};
    int niter = (deg + 1) >> 1;
    for (int it = 0; it < niter; ++it) {
        int idx = 2 * it + sgl;
        int t = beg + idx;
        bool valid = t < end;
        int c = hcol[valid ? t : beg];
        float w;
        if (idx < 32) w = s_w[wslot][hb + idx];
        else          w = valid ? eproj[c] * inv_s : 0.f;
        uint4 F = ((const uint4*)(in_bf + (size_t)c * D_DIM))[sl];
        float nf[8];
        unpack_bf8(F, nf);
        #pragma unroll
        for (int j = 0; j < 8; ++j) acc[j] += w * nf[j];
    }

    #pragma unroll
    for (int j = 0; j < 8; ++j) acc[j] += __shfl_xor(acc[j], 16);

    float4 q = (sgl == 0) ? make_float4(acc[0], acc[1], acc[2], acc[3])
                          : make_float4(acc[4], acc[5], acc[6], acc[7]);
    float4 tq = tanh4(q);
    ((float4*)orow)[2 * sl + sgl] = tq;
    if (out_bf != nullptr)
        ((uint2*)(out_bf + (size_t)row * D_DIM))[2 * sl + sgl] = pack_bf4(tq);
    if (ha != nullptr) {
        const float4* ha4 = (const float4*)ha;
        float pdp = dot4(tq, ha4[2 * sl + sgl]);
        pdp = row16_sum(pdp);
        pdp += __shfl_xor(pdp, 16);
        if (ll == 0) eproj_out[row] = __expf(pdp);
    }
}

extern "C" void kernel_launch(void* const* d_in, const int* in_sizes, int n_in,
                              void* d_out, int out_size, void* d_ws, size_t ws_size,
                              hipStream_t stream) {
    const float* features  = (const float*)d_in[0];
    const float* rel_emb   = (const float*)d_in[1];
    const float* r_val     = (const float*)d_in[2];
    const float* attk      = (const float*)d_in[3];
    const float* high_atts = (const float*)d_in[4];
    const int*   adj       = (const int*)d_in[5];
    const int*   r_index   = (const int*)d_in[6];
    const int*   high_nei  = (const int*)d_in[7];
    float* out = (float*)d_out;

    char* ws = (char*)d_ws;
    auto take = [&](size_t bytes) -> char* {
        char* p = ws;
        ws += (bytes + 255) & ~(size_t)255;
        return p;
    };
    int*   row_ptr_adj  = (int*)take((N_NODES + 1) * sizeof(int));
    int*   row_ptr_high = (int*)take((N_NODES + 1) * sizeof(int));
    float* wtab         = (float*)take(2 * R_REL * sizeof(float));
    float* eproj0       = (float*)take(N_NODES * sizeof(float));
    float* eproj1       = (float*)take(N_NODES * sizeof(float));
    int2*  epack        = (int2*)take((size_t)T_TRI * sizeof(int2));
    u16*   relu_bf      = (u16*)take((size_t)R_REL * D_DIM * sizeof(u16));
    u16*   fbf0         = (u16*)take((size_t)N_NODES * D_DIM * sizeof(u16));
    u16*   fbf1         = (u16*)take((size_t)N_NODES * D_DIM * sizeof(u16));
    u16*   fbf2         = (u16*)take((size_t)N_NODES * D_DIM * sizeof(u16));
    u16*   fbf3         = (u16*)take((size_t)N_NODES * D_DIM * sizeof(u16));

    k_prep<<<4096, 256, 0, stream>>>(features, rel_emb, attk, r_val, out, fbf0,
                                     relu_bf, wtab, adj, r_index, high_nei,
                                     row_ptr_adj, row_ptr_high, epack);

    int pair_blocks = ((N_NODES + 1) / 2 + 3) / 4;   // 2 rows/wave, 4 waves/block

    k_nr_layer<<<pair_blocks, 256, 0, stream>>>(
        out, 1 * D_DIM, fbf0, fbf1,
        row_ptr_adj, epack, relu_bf, wtab + 0 * R_REL, nullptr, nullptr);
    k_nr_layer<<<pair_blocks, 256, 0, stream>>>(
        out, 2 * D_DIM, fbf1, fbf2,
        row_ptr_adj, epack, relu_bf, wtab + 1 * R_REL,
        high_atts + 0 * D_DIM, eproj0);
    k_high_layer<<<pair_blocks, 256, 0, stream>>>(
        out, 3 * D_DIM, fbf2, fbf3,
        row_ptr_high, high_nei + T_TRI, eproj0, high_atts + 1 * D_DIM, eproj1);
    k_high_layer<<<pair_blocks, 256, 0, stream>>>(
        out, 4 * D_DIM, fbf3, nullptr,
        row_ptr_high, high_nei + T_TRI, eproj1, nullptr, nullptr);
}

// Round 15
// 198.964 us; speedup vs baseline: 1.0764x; 1.0764x over previous
//
#include <hip/hip_runtime.h>
#include <math.h>

#define N_NODES 100000
#define R_REL   1000
#define T_TRI   600000
#define D_DIM   128
#define OUT_STRIDE 640

typedef unsigned int  u32;
typedef unsigned short u16;
typedef float nfloat4 __attribute__((ext_vector_type(4)));   // native vec for nt builtins

template<int CTRL>
__device__ __forceinline__ float dpp_add(float x) {
    int xi = __float_as_int(x);
    int r = __builtin_amdgcn_update_dpp(xi, xi, CTRL, 0xf, 0xf, false);
    return x + __int_as_float(r);
}
__device__ __forceinline__ float row16_sum(float v) {
    v = dpp_add<0x121>(v);
    v = dpp_add<0x122>(v);
    v = dpp_add<0x124>(v);
    v = dpp_add<0x128>(v);
    return v;
}
__device__ __forceinline__ float wave_sum(float v) {
    #pragma unroll
    for (int off = 32; off > 0; off >>= 1) v += __shfl_xor(v, off);
    return v;
}
__device__ __forceinline__ float half32_sum(float v) {
    v = row16_sum(v);
    v += __shfl_xor(v, 16);
    return v;
}
__device__ __forceinline__ float fast_tanh(float x) {
    float e = __expf(2.f * x);
    return 1.f - __fdividef(2.f, e + 1.f);
}
__device__ __forceinline__ float4 tanh4(float4 v) {
    float4 o; o.x = fast_tanh(v.x); o.y = fast_tanh(v.y);
    o.z = fast_tanh(v.z); o.w = fast_tanh(v.w);
    return o;
}
__device__ __forceinline__ float dot4(float4 a, float4 b) {
    return a.x*b.x + a.y*b.y + a.z*b.z + a.w*b.w;
}
__device__ __forceinline__ u32 bfr(float x) {
    u32 u = __float_as_uint(x);
    return (u + 0x7fffu + ((u >> 16) & 1u)) >> 16;
}
__device__ __forceinline__ uint2 pack_bf4(float4 v) {
    uint2 p;
    p.x = bfr(v.x) | (bfr(v.y) << 16);
    p.y = bfr(v.z) | (bfr(v.w) << 16);
    return p;
}
__device__ __forceinline__ void unpack_bf8(uint4 v, float f[8]) {
    f[0] = __uint_as_float(v.x << 16); f[1] = __uint_as_float(v.x & 0xffff0000u);
    f[2] = __uint_as_float(v.y << 16); f[3] = __uint_as_float(v.y & 0xffff0000u);
    f[4] = __uint_as_float(v.z << 16); f[5] = __uint_as_float(v.z & 0xffff0000u);
    f[6] = __uint_as_float(v.w << 16); f[7] = __uint_as_float(v.w & 0xffff0000u);
}
// non-temporal float4 store via native vector type: output chunks are
// write-once, never re-read on GPU — keep them out of L2/L3 so the bf16
// gather tables stay resident.
__device__ __forceinline__ void nt_store4(float* p, float4 v) {
    nfloat4 nv; nv.x = v.x; nv.y = v.y; nv.z = v.z; nv.w = v.w;
    __builtin_nontemporal_store(nv, (nfloat4*)p);
}

// prep: tanh+pack chunk0, normalized-rel, rowptrs, packed edge array
__global__ void k_prep(const float* __restrict__ feat, const float* __restrict__ rel,
                       const float* __restrict__ attk, const float* __restrict__ r_val,
                       float* __restrict__ out, u16* __restrict__ bf0,
                       u16* __restrict__ relu_bf, float* __restrict__ wtab,
                       const int* __restrict__ adj, const int* __restrict__ r_index,
                       const int* __restrict__ hn_rows,
                       int* __restrict__ rpa, int* __restrict__ rph,
                       int2* __restrict__ epack) {
    int tid = threadIdx.x;
    int gt = blockIdx.x * blockDim.x + tid;
    int gstride = gridDim.x * blockDim.x;

    for (int i = gt; i < N_NODES * D_DIM / 4; i += gstride) {
        int n = i >> 5, d4 = i & 31;
        float4 v = ((const float4*)feat)[i];
        float4 t = tanh4(v);
        nt_store4(out + (size_t)n * OUT_STRIDE + 4 * d4, t);
        ((uint2*)(bf0 + (size_t)n * D_DIM))[d4] = pack_bf4(t);
    }
    int gw = gt >> 6, lane = tid & 63;
    int nwaves = gstride >> 6;
    for (int r = gw; r < R_REL; r += nwaves) {
        float2 a  = ((const float2*)rel)[r * 64 + lane];
        float2 k0 = ((const float2*)attk)[lane];
        float2 k1 = ((const float2*)(attk + D_DIM))[lane];
        float nrm2 = wave_sum(a.x * a.x + a.y * a.y);
        float d0 = wave_sum(a.x * k0.x + a.y * k0.y);
        float d1 = wave_sum(a.x * k1.x + a.y * k1.y);
        float inv = __frsqrt_rn(nrm2);
        ((u32*)relu_bf)[r * 64 + lane] = bfr(a.x * inv) | (bfr(a.y * inv) << 16);
        if (lane == 0) {
            wtab[r]         = __expf(d0 * inv);
            wtab[R_REL + r] = __expf(d1 * inv);
        }
    }
    for (int i = gt; i < 2 * (N_NODES + 1); i += gstride) {
        const int* rows; int* p; int n;
        if (i <= N_NODES) { rows = adj; p = rpa; n = i; }
        else { rows = hn_rows; p = rph; n = i - (N_NODES + 1); }
        int lo = 0, hi = T_TRI;
        while (lo < hi) { int m = (lo + hi) >> 1; if (rows[m] < n) lo = m + 1; else hi = m; }
        p[n] = lo;
    }
    // packed edges: (col, rel | zflag<<31)
    for (int t = gt; t < T_TRI; t += gstride) {
        int c  = adj[T_TRI + t];
        int rt = r_index[T_TRI + t];
        if (r_val[t] == 0.f) rt |= 0x80000000;
        epack[t] = make_int2(c, rt);
    }
}

// 2 rows/wave, 2x16-lane subgroups per row, 8 dims/lane.
__global__ __launch_bounds__(256) void k_nr_layer(
    float* __restrict__ outbuf, int out_off,
    const u16* __restrict__ in_bf,
    u16* __restrict__ out_bf,
    const int* __restrict__ row_ptr,
    const int2* __restrict__ epack,
    const u16* __restrict__ relu_bf,
    const float* __restrict__ wtab,
    const float* __restrict__ ha,
    float* __restrict__ eproj_out) {
    __shared__ float s_w[4][64];
    int wslot = threadIdx.x >> 6;
    int lane  = threadIdx.x & 63;
    int wid2  = (blockIdx.x * blockDim.x + threadIdx.x) >> 6;
    int row   = wid2 * 2 + (lane >> 5);
    if (row >= N_NODES) return;
    int ll  = lane & 31;
    int sgl = (lane >> 4) & 1;
    int sl  = lane & 15;
    int beg = row_ptr[row], end = row_ptr[row + 1];
    int deg = end - beg;
    float* orow = outbuf + (size_t)row * OUT_STRIDE + out_off;

    if (deg == 0) {
        float4 z = {0.f,0.f,0.f,0.f};
        nt_store4(orow + 4 * ll, z);
        if (out_bf != nullptr && ll < 16) {
            uint4 zz = {0u,0u,0u,0u};
            ((uint4*)(out_bf + (size_t)row * D_DIM))[ll] = zz;
        }
        if (ha != nullptr && ll == 0) eproj_out[row] = 1.f;
        return;
    }

    // pass A: lane ll owns edge beg+ll
    int  t0 = beg + ll;
    bool va = t0 < end;
    int2 ea = epack[va ? t0 : beg];
    int  rt_a = ea.y & 0x7fffffff;
    bool z_a  = ea.y < 0;
    float w_a = va ? (z_a ? 1.f : wtab[rt_a]) : 0.f;
    float lsum = w_a;
    for (int t = t0 + 32; t < end; t += 32) {          // deg>32 guard
        int2 e = epack[t];
        lsum += (e.y < 0) ? 1.f : wtab[e.y & 0x7fffffff];
    }
    float inv_s = 1.f / half32_sum(lsum);
    float sw = w_a * inv_s;
    s_w[wslot][lane] = z_a ? -sw : sw;
    int hb = lane & 32;

    float acc[8] = {0.f,0.f,0.f,0.f,0.f,0.f,0.f,0.f};
    int niter = (deg + 1) >> 1;
    for (int it = 0; it < niter; ++it) {
        int idx = 2 * it + sgl;
        int t = beg + idx;
        bool valid = t < end;
        int2 e = epack[valid ? t : beg];
        int c  = e.x;
        int rt = e.y & 0x7fffffff;
        float sv;
        if (idx < 32) sv = s_w[wslot][hb + idx];       // signed; 0 beyond deg
        else {
            bool z = e.y < 0;
            float wv = valid ? (z ? 1.f : wtab[rt]) * inv_s : 0.f;
            sv = z ? -wv : wv;
        }
        float w = fabsf(sv);
        uint4 F = ((const uint4*)(in_bf   + (size_t)c  * D_DIM))[sl];
        uint4 U = ((const uint4*)(relu_bf + (size_t)rt * D_DIM))[sl];
        float nf[8], uf[8];
        unpack_bf8(F, nf); unpack_bf8(U, uf);
        float pd = 0.f;
        #pragma unroll
        for (int j = 0; j < 8; ++j) pd += nf[j] * uf[j];
        pd = row16_sum(pd);
        float bt = (sv < 0.f) ? 0.f : 2.f * w * pd;
        #pragma unroll
        for (int j = 0; j < 8; ++j) acc[j] += w * nf[j] - bt * uf[j];
    }

    #pragma unroll
    for (int j = 0; j < 8; ++j) acc[j] += __shfl_xor(acc[j], 16);

    float4 q = (sgl == 0) ? make_float4(acc[0], acc[1], acc[2], acc[3])
                          : make_float4(acc[4], acc[5], acc[6], acc[7]);
    float4 tq = tanh4(q);
    nt_store4(orow + 4 * (2 * sl + sgl), tq);
    if (out_bf != nullptr)
        ((uint2*)(out_bf + (size_t)row * D_DIM))[2 * sl + sgl] = pack_bf4(tq);
    if (ha != nullptr) {
        const float4* ha4 = (const float4*)ha;
        float pdp = dot4(tq, ha4[2 * sl + sgl]);
        pdp = row16_sum(pdp);
        pdp += __shfl_xor(pdp, 16);
        if (ll == 0) eproj_out[row] = __expf(pdp);
    }
}

__global__ __launch_bounds__(256) void k_high_layer(
    float* __restrict__ outbuf, int out_off,
    const u16* __restrict__ in_bf,
    u16* __restrict__ out_bf,
    const int* __restrict__ row_ptr,
    const int* __restrict__ hcol,
    const float* __restrict__ eproj,
    const float* __restrict__ ha,
    float* __restrict__ eproj_out) {
    __shared__ float s_w[4][64];
    int wslot = threadIdx.x >> 6;
    int lane  = threadIdx.x & 63;
    int wid2  = (blockIdx.x * blockDim.x + threadIdx.x) >> 6;
    int row   = wid2 * 2 + (lane >> 5);
    if (row >= N_NODES) return;
    int ll  = lane & 31;
    int sgl = (lane >> 4) & 1;
    int sl  = lane & 15;
    int beg = row_ptr[row], end = row_ptr[row + 1];
    int deg = end - beg;
    float* orow = outbuf + (size_t)row * OUT_STRIDE + out_off;

    if (deg == 0) {
        float4 z = {0.f,0.f,0.f,0.f};
        nt_store4(orow + 4 * ll, z);
        if (out_bf != nullptr && ll < 16) {
            uint4 zz = {0u,0u,0u,0u};
            ((uint4*)(out_bf + (size_t)row * D_DIM))[ll] = zz;
        }
        if (ha != nullptr && ll == 0) eproj_out[row] = 1.f;
        return;
    }

    int  t0 = beg + ll;
    bool va = t0 < end;
    float e_a = va ? eproj[hcol[t0]] : 0.f;
    float lsum = e_a;
    for (int t = t0 + 32; t < end; t += 32)
        lsum += eproj[hcol[t]];
    float inv_s = 1.f / half32_sum(lsum);
    s_w[wslot][lane] = e_a * inv_s;
    int hb = lane & 32;

    float acc[8] = {0.f,0.f,0.f,0.f,0.f,0.f,0.f,0.f};
    int niter = (deg + 1) >> 1;
    for (int it = 0; it < niter; ++it) {
        int idx = 2 * it + sgl;
        int t = beg + idx;
        bool valid = t < end;
        int c = hcol[valid ? t : beg];
        float w;
        if (idx < 32) w = s_w[wslot][hb + idx];
        else          w = valid ? eproj[c] * inv_s : 0.f;
        uint4 F = ((const uint4*)(in_bf + (size_t)c * D_DIM))[sl];
        float nf[8];
        unpack_bf8(F, nf);
        #pragma unroll
        for (int j = 0; j < 8; ++j) acc[j] += w * nf[j];
    }

    #pragma unroll
    for (int j = 0; j < 8; ++j) acc[j] += __shfl_xor(acc[j], 16);

    float4 q = (sgl == 0) ? make_float4(acc[0], acc[1], acc[2], acc[3])
                          : make_float4(acc[4], acc[5], acc[6], acc[7]);
    float4 tq = tanh4(q);
    nt_store4(orow + 4 * (2 * sl + sgl), tq);
    if (out_bf != nullptr)
        ((uint2*)(out_bf + (size_t)row * D_DIM))[2 * sl + sgl] = pack_bf4(tq);
    if (ha != nullptr) {
        const float4* ha4 = (const float4*)ha;
        float pdp = dot4(tq, ha4[2 * sl + sgl]);
        pdp = row16_sum(pdp);
        pdp += __shfl_xor(pdp, 16);
        if (ll == 0) eproj_out[row] = __expf(pdp);
    }
}

extern "C" void kernel_launch(void* const* d_in, const int* in_sizes, int n_in,
                              void* d_out, int out_size, void* d_ws, size_t ws_size,
                              hipStream_t stream) {
    const float* features  = (const float*)d_in[0];
    const float* rel_emb   = (const float*)d_in[1];
    const float* r_val     = (const float*)d_in[2];
    const float* attk      = (const float*)d_in[3];
    const float* high_atts = (const float*)d_in[4];
    const int*   adj       = (const int*)d_in[5];
    const int*   r_index   = (const int*)d_in[6];
    const int*   high_nei  = (const int*)d_in[7];
    float* out = (float*)d_out;

    char* ws = (char*)d_ws;
    auto take = [&](size_t bytes) -> char* {
        char* p = ws;
        ws += (bytes + 255) & ~(size_t)255;
        return p;
    };
    int*   row_ptr_adj  = (int*)take((N_NODES + 1) * sizeof(int));
    int*   row_ptr_high = (int*)take((N_NODES + 1) * sizeof(int));
    float* wtab         = (float*)take(2 * R_REL * sizeof(float));
    float* eproj0       = (float*)take(N_NODES * sizeof(float));
    float* eproj1       = (float*)take(N_NODES * sizeof(float));
    int2*  epack        = (int2*)take((size_t)T_TRI * sizeof(int2));
    u16*   relu_bf      = (u16*)take((size_t)R_REL * D_DIM * sizeof(u16));
    u16*   fbf0         = (u16*)take((size_t)N_NODES * D_DIM * sizeof(u16));
    u16*   fbf1         = (u16*)take((size_t)N_NODES * D_DIM * sizeof(u16));
    u16*   fbf2         = (u16*)take((size_t)N_NODES * D_DIM * sizeof(u16));
    u16*   fbf3         = (u16*)take((size_t)N_NODES * D_DIM * sizeof(u16));

    k_prep<<<4096, 256, 0, stream>>>(features, rel_emb, attk, r_val, out, fbf0,
                                     relu_bf, wtab, adj, r_index, high_nei,
                                     row_ptr_adj, row_ptr_high, epack);

    int pair_blocks = ((N_NODES + 1) / 2 + 3) / 4;   // 2 rows/wave, 4 waves/block

    k_nr_layer<<<pair_blocks, 256, 0, stream>>>(
        out, 1 * D_DIM, fbf0, fbf1,
        row_ptr_adj, epack, relu_bf, wtab + 0 * R_REL, nullptr, nullptr);
    k_nr_layer<<<pair_blocks, 256, 0, stream>>>(
        out, 2 * D_DIM, fbf1, fbf2,
        row_ptr_adj, epack, relu_bf, wtab + 1 * R_REL,
        high_atts + 0 * D_DIM, eproj0);
    k_high_layer<<<pair_blocks, 256, 0, stream>>>(
        out, 3 * D_DIM, fbf2, fbf3,
        row_ptr_high, high_nei + T_TRI, eproj0, high_atts + 1 * D_DIM, eproj1);
    k_high_layer<<<pair_blocks, 256, 0, stream>>>(
        out, 4 * D_DIM, fbf3, nullptr,
        row_ptr_high, high_nei + T_TRI, eproj1, nullptr, nullptr);
}